// Round 18
// baseline (230.800 us; speedup 1.0000x reference)
//
#include <hip/hip_runtime.h>

#define HH 1024
#define WW 1024
#define NB 16
#define NTH 3
#define BAND 128
#define NBAND (HH/BAND)       // 8
#define NSTRIP 11             // strips of 128 cols, 96-col yield
#define ACC_BYTES 4096
#define NEGBIG -1e30f
#define RING 49               // 41 live rows + 8-row write group
#define L10 14.426950408889634f   // 10*log2(e)

typedef unsigned int u32;
typedef _Float16 hv __attribute__((ext_vector_type(2)));

__device__ __forceinline__ hv pkh(float a, float b){
  auto t = __builtin_amdgcn_cvt_pkrtz(a, b);
  hv r; __builtin_memcpy(&r, &t, 4); return r;
}
__device__ __forceinline__ hv bph(int idx4, hv v){
  int s; __builtin_memcpy(&s, &v, 4);
  const int r = __builtin_amdgcn_ds_bpermute(idx4, s);
  hv o; __builtin_memcpy(&o, &r, 4); return o;
}
__device__ __forceinline__ hv swph(hv v){
  u32 u; __builtin_memcpy(&u, &v, 4);
  u = (u >> 16) | (u << 16);
  hv o; __builtin_memcpy(&o, &u, 4); return o;
}
// raw stats: sd += 2*(h.f-h.o)^2 ; sr += h.f^2+h.o^2  (normalized in fss_final)
__device__ __forceinline__ void dstat(hv h, float& sd, float& sr){
  const hv d = h - swph(h);
  sd = __builtin_amdgcn_fdot2(d, d, sd, false);
  sr = __builtin_amdgcn_fdot2(h, h, sr, false);
}

#if __has_builtin(__builtin_amdgcn_rcpf)
#define RCP(x) __builtin_amdgcn_rcpf(x)
#else
#define RCP(x) (1.0f/(x))
#endif
#if __has_builtin(__builtin_amdgcn_exp2f)
#define EXP2(x) __builtin_amdgcn_exp2f(x)
#else
#define EXP2(x) exp2f(x)
#endif

// pack e = 2^(-L10*v) with the 3 obs bits stuffed in mantissa bits [2:0]
__device__ __forceinline__ u32 packeo(float v, float o){
  const float e = EXP2(-L10 * v);           // OOB (v=NEGBIG) -> +inf -> sig 0
  u32 w = __float_as_uint(e) & ~7u;
  w |= (o > 0.0f) ? 1u : 0u;
  w |= (o > 0.5f) ? 2u : 0u;
  w |= (o > 1.0f) ? 4u : 0u;
  return w;
}

__global__ __launch_bounds__(192) void fss_fused(
    const float* __restrict__ F_, const float* __restrict__ O_,
    double* __restrict__ accum)
{
  const int tid = threadIdx.x;
  const int ln  = tid & 63;
  const int t   = tid >> 6;                    // threshold index = wave id
  const int b   = blockIdx.x;
  const int s   = b % NSTRIP;
  const int rem = b / NSTRIP;
  const int band = rem & (NBAND-1);
  const int img  = rem / NBAND;
  const int y0 = band * BAND;
  const int xbase = 96*s - 16;
  const int x0 = xbase + 2*ln;
  const bool colok = ((unsigned)x0 < WW);
  const bool act = (ln >= 8) && (ln < 56) && colok;

  const float K = (t==0) ? 1.0f : ((t==1) ? 148.41315910257660f : 22026.465794806718f);
  const u32 bm = 1u << t;

  const float* F = F_ + (size_t)img*HH*WW;
  const float* O = O_ + (size_t)img*HH*WW;

  __shared__ u32 ring[RING][128];   // e (f32 bits, mantissa[2:0] = obs bits)

  auto slotof = [](int r){ int m = r % RING; return (m < 0) ? m + RING : m; };

  // stage row r (cols 2ln, 2ln+1) into the ring — caller-assigned rows only
  auto stage = [&](int r){
    float2 fv = {NEGBIG, NEGBIG}, ov = {NEGBIG, NEGBIG};
    if ((unsigned)r < HH && colok){
      fv = *(const float2*)&F[(size_t)r*WW + x0];
      ov = *(const float2*)&O[(size_t)r*WW + x0];
    }
    uint2 w; w.x = packeo(fv.x, ov.x); w.y = packeo(fv.y, ov.y);
    *(uint2*)&ring[slotof(r)][2*ln] = w;
  };

  // single-threshold vertical window state + raw stats
  float c9f0=0, c9f1=0, c9o0=0, c9o1=0, c33f0=0, c33f1=0, c33o0=0, c33o1=0;
  float s1d=0, s1r=0, s9d=0, s9r=0, s33d=0, s33r=0;

  const int i_m1=((ln-1)&63)<<2, i_m2=((ln-2)&63)<<2, i_m4=((ln-4)&63)<<2, i_m8=((ln-8)&63)<<2;
  const int i_p1=((ln+1)&63)<<2, i_p2=((ln+2)&63)<<2, i_p7=((ln+7)&63)<<2, i_p8=((ln+8)&63)<<2;

  // unpack one packed word -> sig (f32) and obs (0/1)
  #define UNP(w, SF, SO) \
    const float SF = RCP(__builtin_fmaf(__uint_as_float((w) & ~7u), K, 1.0f)); \
    const float SO = ((w) & bm) ? 1.f : 0.f;

  // ---- prologue: stage rows y0-16 .. y0+24 (41 rows), split across 3 waves ----
  #pragma unroll 1
  for (int k = t; k < 41; k += 3) stage(y0-16+k);
  __syncthreads();

  // ---- warmup from ring: rows y0-16 .. y0+16 ----
  {
    int sw = slotof(y0-16);
    #pragma unroll 1
    for (int r = y0-16; r <= y0+16; ++r){
      const uint2 w = *(const uint2*)&ring[sw][2*ln];
      sw++; if (sw == RING) sw = 0;
      UNP(w.x, sf0, so0); UNP(w.y, sf1, so1);
      c33f0 += sf0; c33f1 += sf1; c33o0 += so0; c33o1 += so1;
      if (r >= y0-4 && r <= y0+4){ c9f0 += sf0; c9f1 += sf1; c9o0 += so0; c9o1 += so1; }
      if (r >= y0 && r <= y0+4){
        const float d0 = sf0-so0, d1 = sf1-so1;
        s1d += d0*d0 + d1*d1;
        s1r += sf0*sf0 + so0 + sf1*sf1 + so1;    // so^2 == so
      }
    }
  }

  // ---- main loop: {prefetch, 8 rows (reads-early), write, ONE barrier} ----
  int si9 = slotof(y0+5), so9 = slotof(y0-4), si33 = slotof(y0+17), so33 = slotof(y0-16);
  int wrb = slotof(y0+25);

  #pragma unroll 1
  for (int g = y0; g < y0 + BAND; g += 8){
    // prefetch this wave's staging rows (rows g+25..g+32, rows j%3==t)
    float2 vf[3], vo[3]; int nst = 0; int rws[3];
    #pragma unroll
    for (int j = 0; j < 8; ++j){
      if (j % 3 == t){
        const int r = g + 25 + j;
        rws[nst] = r;
        vf[nst] = make_float2(NEGBIG, NEGBIG);
        vo[nst] = make_float2(NEGBIG, NEGBIG);
        if ((unsigned)r < HH && colok){
          vf[nst] = *(const float2*)&F[(size_t)r*WW + x0];
          vo[nst] = *(const float2*)&O[(size_t)r*WW + x0];
        }
        nst++;
      }
    }

    // 8 compute rows (reads rows [g-16, g+24], all resident)
    #pragma unroll 1
    for (int j = 0; j < 8; ++j){
      const int y = g + j;

      // issue the 4 ring reads FIRST (independent of the bpermute chain)
      const uint2 wi9  = *(const uint2*)&ring[si9 ][2*ln];
      const uint2 wo9  = *(const uint2*)&ring[so9 ][2*ln];
      const uint2 wi33 = *(const uint2*)&ring[si33][2*ln];
      const uint2 wo33 = *(const uint2*)&ring[so33][2*ln];

      // horizontal windows + raw stats for row y
      {
        hv wv = pkh(c33f0 + c33f1, c33o0 + c33o1);
        wv = wv + bph(i_m1, wv);
        wv = wv + bph(i_m2, wv);
        wv = wv + bph(i_m4, wv);
        wv = wv + bph(i_m8, wv);
        const hv c0 = pkh(c33f0, c33o0);
        const hv c1 = pkh(c33f1, c33o1);
        const hv h33_0 = bph(i_p7, wv) + bph(i_p8, c0);
        const hv h33_1 = bph(i_p8, wv) + bph(i_m8, c1);

        const hv q  = pkh(c9f0 + c9f1, c9o0 + c9o1);
        const hv q0 = pkh(c9f0, c9o0);
        const hv q1 = pkh(c9f1, c9o1);
        const hv mid = q + bph(i_m1, q) + bph(i_p1, q);
        const hv h9_0 = mid + bph(i_m2, q) + bph(i_p2, q0);
        const hv h9_1 = mid + bph(i_p2, q) + bph(i_m2, q1);

        dstat(h9_0,  s9d,  s9r);
        dstat(h9_1,  s9d,  s9r);
        dstat(h33_0, s33d, s33r);
        dstat(h33_1, s33d, s33r);
      }

      // slide vertical windows to center y+1 from the already-read words
      {
        { // entering 9-row (+ k=1 stats)
          UNP(wi9.x, sf0, so0); UNP(wi9.y, sf1, so1);
          c9f0 += sf0; c9f1 += sf1; c9o0 += so0; c9o1 += so1;
          if (y+5 < y0 + BAND){
            const float d0 = sf0-so0, d1 = sf1-so1;
            s1d += d0*d0 + d1*d1;
            s1r += sf0*sf0 + so0 + sf1*sf1 + so1;
          }
        }
        { // leaving 9-row
          UNP(wo9.x, sf0, so0); UNP(wo9.y, sf1, so1);
          c9f0 -= sf0; c9f1 -= sf1; c9o0 -= so0; c9o1 -= so1;
        }
        { // entering 33-row
          UNP(wi33.x, sf0, so0); UNP(wi33.y, sf1, so1);
          c33f0 += sf0; c33f1 += sf1; c33o0 += so0; c33o1 += so1;
        }
        { // leaving 33-row
          UNP(wo33.x, sf0, so0); UNP(wo33.y, sf1, so1);
          c33f0 -= sf0; c33f1 -= sf1; c33o0 -= so0; c33o1 -= so1;
        }
        si9++;  if (si9  == RING) si9  = 0;
        so9++;  if (so9  == RING) so9  = 0;
        si33++; if (si33 == RING) si33 = 0;
        so33++; if (so33 == RING) so33 = 0;
      }
    }

    // write staged rows: their slots (rows g-24..g-17) died at iter g-8,
    // so no pre-write barrier is needed; one barrier publishes for iter g+8.
    #pragma unroll
    for (int k = 0; k < 3; ++k){
      if (k < nst){
        const int r = rws[k];
        int wslt = wrb + (r - (g + 25)); if (wslt >= RING) wslt -= RING;
        uint2 w; w.x = packeo(vf[k].x, vo[k].x); w.y = packeo(vf[k].y, vo[k].y);
        *(uint2*)&ring[wslt][2*ln] = w;
      }
    }
    wrb += 8; if (wrb >= RING) wrb -= RING;
    __syncthreads();
  }

  // ---- mask halo lanes, wave-reduce, per-wave f64 atomics ----
  if (!act){ s1d=0; s1r=0; s9d=0; s9r=0; s33d=0; s33r=0; }
  #define WRED(v) { _Pragma("unroll") \
    for (int d = 32; d; d >>= 1) v += __shfl_down(v, (unsigned)d, 64); }
  WRED(s1d);  WRED(s1r);
  WRED(s9d);  WRED(s9r);
  WRED(s33d); WRED(s33r);
  if (ln == 0){
    double* a = accum + (size_t)(img*NTH + t)*6;
    atomicAdd(&a[0], (double)s1d);
    atomicAdd(&a[1], (double)s1r);
    atomicAdd(&a[2], (double)s9d);
    atomicAdd(&a[3], (double)s9r);
    atomicAdd(&a[4], (double)s33d);
    atomicAdd(&a[5], (double)s33r);
  }
}

__global__ void fss_final(const double* __restrict__ accum, float* __restrict__ out)
{
  if (threadIdx.x == 0 && blockIdx.x == 0){
    const double HW = (double)HH * (double)WW;
    const double msc[3] = {1.0, 2.0*6561.0, 2.0*1185921.0};
    const double rsc[3] = {1.0, 6561.0, 1185921.0};
    double total = 0.0;
    for (int t = 0; t < NTH; ++t){
      for (int k = 0; k < 3; ++k){
        double sum = 0.0;
        for (int img = 0; img < NB; ++img){
          const double* a = accum + (size_t)(img*NTH + t)*6 + (size_t)k*2;
          const double mse  = a[0] / (msc[k]*HW);
          const double mref = a[1] / (rsc[k]*HW);
          sum += 1.0 - mse / (mref + 1e-8);
        }
        total += sum / (double)NB;
      }
    }
    out[0] = (float)(1.0 - total/9.0);
  }
}

extern "C" void kernel_launch(void* const* d_in, const int* in_sizes, int n_in,
                              void* d_out, int out_size, void* d_ws, size_t ws_size,
                              hipStream_t stream)
{
  const float* fcst = (const float*)d_in[0];
  const float* obs  = (const float*)d_in[1];
  float* out = (float*)d_out;
  double* accum = (double*)d_ws;

  const int nblocks = NSTRIP * NBAND * NB;   // 1408 blocks x 3 waves

  hipMemsetAsync(d_ws, 0, ACC_BYTES, stream);
  hipLaunchKernelGGL(fss_fused, dim3(nblocks), dim3(192), 0, stream,
                     fcst, obs, accum);
  hipLaunchKernelGGL(fss_final, dim3(1), dim3(64), 0, stream, accum, out);
}

// Round 19
// 229.844 us; speedup vs baseline: 1.0042x; 1.0042x over previous
//
#include <hip/hip_runtime.h>

#define HH 1024
#define WW 1024
#define NB 16
#define NTH 3
#define BAND 128
#define NBAND (HH/BAND)       // 8
#define NSTRIP 11             // strips of 128 cols, 96-col yield
#define ACC_BYTES 4096
#define NEGBIG -1e30f
#define RING 49               // 41 live rows + 8-row write group
#define L10 14.426950408889634f   // 10*log2(e)

typedef unsigned int u32;
typedef _Float16 hv __attribute__((ext_vector_type(2)));

__device__ __forceinline__ hv pkh(float a, float b){
  auto t = __builtin_amdgcn_cvt_pkrtz(a, b);
  hv r; __builtin_memcpy(&r, &t, 4); return r;
}
__device__ __forceinline__ hv bph(int idx4, hv v){
  int s; __builtin_memcpy(&s, &v, 4);
  const int r = __builtin_amdgcn_ds_bpermute(idx4, s);
  hv o; __builtin_memcpy(&o, &r, 4); return o;
}
__device__ __forceinline__ hv swph(hv v){
  u32 u; __builtin_memcpy(&u, &v, 4);
  u = (u >> 16) | (u << 16);
  hv o; __builtin_memcpy(&o, &u, 4); return o;
}
// raw stats: sd += 2*(h.f-h.o)^2 ; sr += h.f^2+h.o^2  (normalized in fss_final)
__device__ __forceinline__ void dstat(hv h, float& sd, float& sr){
  const hv d = h - swph(h);
  sd = __builtin_amdgcn_fdot2(d, d, sd, false);
  sr = __builtin_amdgcn_fdot2(h, h, sr, false);
}

#if __has_builtin(__builtin_amdgcn_rcpf)
#define RCP(x) __builtin_amdgcn_rcpf(x)
#else
#define RCP(x) (1.0f/(x))
#endif
#if __has_builtin(__builtin_amdgcn_exp2f)
#define EXP2(x) __builtin_amdgcn_exp2f(x)
#else
#define EXP2(x) exp2f(x)
#endif

// pack e = 2^(-L10*v) with the 3 obs bits stuffed in mantissa bits [2:0]
__device__ __forceinline__ u32 packeo(float v, float o){
  const float e = EXP2(-L10 * v);           // OOB (v=NEGBIG) -> +inf -> sig 0
  u32 w = __float_as_uint(e) & ~7u;
  w |= (o > 0.0f) ? 1u : 0u;
  w |= (o > 0.5f) ? 2u : 0u;
  w |= (o > 1.0f) ? 4u : 0u;
  return w;
}

__global__ __launch_bounds__(192) void fss_fused(
    const float* __restrict__ F_, const float* __restrict__ O_,
    double* __restrict__ accum)
{
  const int tid = threadIdx.x;
  const int ln  = tid & 63;
  const int t   = tid >> 6;                    // threshold index = wave id
  const int b   = blockIdx.x;
  const int s   = b % NSTRIP;
  const int rem = b / NSTRIP;
  const int band = rem & (NBAND-1);
  const int img  = rem / NBAND;
  const int y0 = band * BAND;
  const int xbase = 96*s - 16;
  const int x0 = xbase + 2*ln;
  const bool colok = ((unsigned)x0 < WW);
  const bool act = (ln >= 8) && (ln < 56) && colok;

  const float K = (t==0) ? 1.0f : ((t==1) ? 148.41315910257660f : 22026.465794806718f);
  const u32 bm = 1u << t;

  const float* F = F_ + (size_t)img*HH*WW;
  const float* O = O_ + (size_t)img*HH*WW;

  __shared__ u32 ring[RING][128];   // e (f32 bits, mantissa[2:0] = obs bits)

  auto slotof = [](int r){ int m = r % RING; return (m < 0) ? m + RING : m; };

  auto stage = [&](int r){
    float2 fv = {NEGBIG, NEGBIG}, ov = {NEGBIG, NEGBIG};
    if ((unsigned)r < HH && colok){
      fv = *(const float2*)&F[(size_t)r*WW + x0];
      ov = *(const float2*)&O[(size_t)r*WW + x0];
    }
    uint2 w; w.x = packeo(fv.x, ov.x); w.y = packeo(fv.y, ov.y);
    *(uint2*)&ring[slotof(r)][2*ln] = w;
  };

  // single-threshold vertical window state + raw stats
  float c9f0=0, c9f1=0, c9o0=0, c9o1=0, c33f0=0, c33f1=0, c33o0=0, c33o1=0;
  float s1d=0, s1r=0, s9d=0, s9r=0, s33d=0, s33r=0;

  const int i_m1=((ln-1)&63)<<2, i_m2=((ln-2)&63)<<2, i_m4=((ln-4)&63)<<2, i_m8=((ln-8)&63)<<2;
  const int i_p1=((ln+1)&63)<<2, i_p2=((ln+2)&63)<<2, i_p7=((ln+7)&63)<<2, i_p8=((ln+8)&63)<<2;

  #define UNP(w, SF, SO) \
    const float SF = RCP(__builtin_fmaf(__uint_as_float((w) & ~7u), K, 1.0f)); \
    const float SO = ((w) & bm) ? 1.f : 0.f;

  // ---- prologue: stage rows y0-16 .. y0+24 (41 rows), split across 3 waves ----
  #pragma unroll 1
  for (int k = t; k < 41; k += 3) stage(y0-16+k);
  __syncthreads();

  // ---- warmup from ring: rows y0-16 .. y0+16 ----
  {
    int sw = slotof(y0-16);
    #pragma unroll 1
    for (int r = y0-16; r <= y0+16; ++r){
      const uint2 w = *(const uint2*)&ring[sw][2*ln];
      sw++; if (sw == RING) sw = 0;
      UNP(w.x, sf0, so0); UNP(w.y, sf1, so1);
      c33f0 += sf0; c33f1 += sf1; c33o0 += so0; c33o1 += so1;
      if (r >= y0-4 && r <= y0+4){ c9f0 += sf0; c9f1 += sf1; c9o0 += so0; c9o1 += so1; }
      if (r >= y0 && r <= y0+4){
        const float d0 = sf0-so0, d1 = sf1-so1;
        s1d += d0*d0 + d1*d1;
        s1r += sf0*sf0 + so0 + sf1*sf1 + so1;    // so^2 == so
      }
    }
  }

  // ---- main loop: {static-indexed prefetch, 8 rows, write, ONE barrier} ----
  int si9 = slotof(y0+5), so9 = slotof(y0-4), si33 = slotof(y0+17), so33 = slotof(y0-16);
  int wrb = slotof(y0+25);

  #pragma unroll 1
  for (int g = y0; g < y0 + BAND; g += 8){
    // wave t stages rows j = 3k + t (k static) -> vf[k]/vo[k] statically indexed
    float2 vf[3], vo[3];
    #pragma unroll
    for (int k = 0; k < 3; ++k){
      vf[k] = make_float2(NEGBIG, NEGBIG);
      vo[k] = make_float2(NEGBIG, NEGBIG);
      const int j = 3*k + t;
      if (j < 8){
        const int r = g + 25 + j;
        if ((unsigned)r < HH && colok){
          vf[k] = *(const float2*)&F[(size_t)r*WW + x0];
          vo[k] = *(const float2*)&O[(size_t)r*WW + x0];
        }
      }
    }

    // 8 compute rows (reads rows [g-16, g+24], all resident)
    #pragma unroll 1
    for (int j = 0; j < 8; ++j){
      const int y = g + j;

      // issue the 4 ring reads FIRST (independent of the bpermute chain)
      const uint2 wi9  = *(const uint2*)&ring[si9 ][2*ln];
      const uint2 wo9  = *(const uint2*)&ring[so9 ][2*ln];
      const uint2 wi33 = *(const uint2*)&ring[si33][2*ln];
      const uint2 wo33 = *(const uint2*)&ring[so33][2*ln];

      // horizontal windows + raw stats for row y
      {
        hv wv = pkh(c33f0 + c33f1, c33o0 + c33o1);
        wv = wv + bph(i_m1, wv);
        wv = wv + bph(i_m2, wv);
        wv = wv + bph(i_m4, wv);
        wv = wv + bph(i_m8, wv);
        const hv c0 = pkh(c33f0, c33o0);
        const hv c1 = pkh(c33f1, c33o1);
        const hv h33_0 = bph(i_p7, wv) + bph(i_p8, c0);
        const hv h33_1 = bph(i_p8, wv) + bph(i_m8, c1);

        const hv q  = pkh(c9f0 + c9f1, c9o0 + c9o1);
        const hv q0 = pkh(c9f0, c9o0);
        const hv q1 = pkh(c9f1, c9o1);
        const hv mid = q + bph(i_m1, q) + bph(i_p1, q);
        const hv h9_0 = mid + bph(i_m2, q) + bph(i_p2, q0);
        const hv h9_1 = mid + bph(i_p2, q) + bph(i_m2, q1);

        dstat(h9_0,  s9d,  s9r);
        dstat(h9_1,  s9d,  s9r);
        dstat(h33_0, s33d, s33r);
        dstat(h33_1, s33d, s33r);
      }

      // slide vertical windows to center y+1 from the already-read words
      {
        { // entering 9-row (+ k=1 stats)
          UNP(wi9.x, sf0, so0); UNP(wi9.y, sf1, so1);
          c9f0 += sf0; c9f1 += sf1; c9o0 += so0; c9o1 += so1;
          if (y+5 < y0 + BAND){
            const float d0 = sf0-so0, d1 = sf1-so1;
            s1d += d0*d0 + d1*d1;
            s1r += sf0*sf0 + so0 + sf1*sf1 + so1;
          }
        }
        { // leaving 9-row
          UNP(wo9.x, sf0, so0); UNP(wo9.y, sf1, so1);
          c9f0 -= sf0; c9f1 -= sf1; c9o0 -= so0; c9o1 -= so1;
        }
        { // entering 33-row
          UNP(wi33.x, sf0, so0); UNP(wi33.y, sf1, so1);
          c33f0 += sf0; c33f1 += sf1; c33o0 += so0; c33o1 += so1;
        }
        { // leaving 33-row
          UNP(wo33.x, sf0, so0); UNP(wo33.y, sf1, so1);
          c33f0 -= sf0; c33f1 -= sf1; c33o0 -= so0; c33o1 -= so1;
        }
        si9++;  if (si9  == RING) si9  = 0;
        so9++;  if (so9  == RING) so9  = 0;
        si33++; if (si33 == RING) si33 = 0;
        so33++; if (so33 == RING) so33 = 0;
      }
    }

    // write staged rows: slots (rows g-24..g-17) died at iter g-8 -> no pre-write
    // barrier; the single barrier publishes for iter g+8.
    #pragma unroll
    for (int k = 0; k < 3; ++k){
      const int j = 3*k + t;
      if (j < 8){
        int wslt = wrb + j; if (wslt >= RING) wslt -= RING;
        uint2 w; w.x = packeo(vf[k].x, vo[k].x); w.y = packeo(vf[k].y, vo[k].y);
        *(uint2*)&ring[wslt][2*ln] = w;
      }
    }
    wrb += 8; if (wrb >= RING) wrb -= RING;
    __syncthreads();
  }

  // ---- mask halo lanes, wave-reduce, per-wave f64 atomics ----
  if (!act){ s1d=0; s1r=0; s9d=0; s9r=0; s33d=0; s33r=0; }
  #define WRED(v) { _Pragma("unroll") \
    for (int d = 32; d; d >>= 1) v += __shfl_down(v, (unsigned)d, 64); }
  WRED(s1d);  WRED(s1r);
  WRED(s9d);  WRED(s9r);
  WRED(s33d); WRED(s33r);
  if (ln == 0){
    double* a = accum + (size_t)(img*NTH + t)*6;
    atomicAdd(&a[0], (double)s1d);
    atomicAdd(&a[1], (double)s1r);
    atomicAdd(&a[2], (double)s9d);
    atomicAdd(&a[3], (double)s9r);
    atomicAdd(&a[4], (double)s33d);
    atomicAdd(&a[5], (double)s33r);
  }
}

__global__ void fss_final(const double* __restrict__ accum, float* __restrict__ out)
{
  if (threadIdx.x == 0 && blockIdx.x == 0){
    const double HW = (double)HH * (double)WW;
    const double msc[3] = {1.0, 2.0*6561.0, 2.0*1185921.0};
    const double rsc[3] = {1.0, 6561.0, 1185921.0};
    double total = 0.0;
    for (int t = 0; t < NTH; ++t){
      for (int k = 0; k < 3; ++k){
        double sum = 0.0;
        for (int img = 0; img < NB; ++img){
          const double* a = accum + (size_t)(img*NTH + t)*6 + (size_t)k*2;
          const double mse  = a[0] / (msc[k]*HW);
          const double mref = a[1] / (rsc[k]*HW);
          sum += 1.0 - mse / (mref + 1e-8);
        }
        total += sum / (double)NB;
      }
    }
    out[0] = (float)(1.0 - total/9.0);
  }
}

extern "C" void kernel_launch(void* const* d_in, const int* in_sizes, int n_in,
                              void* d_out, int out_size, void* d_ws, size_t ws_size,
                              hipStream_t stream)
{
  const float* fcst = (const float*)d_in[0];
  const float* obs  = (const float*)d_in[1];
  float* out = (float*)d_out;
  double* accum = (double*)d_ws;

  const int nblocks = NSTRIP * NBAND * NB;   // 1408 blocks x 3 waves

  hipMemsetAsync(d_ws, 0, ACC_BYTES, stream);
  hipLaunchKernelGGL(fss_fused, dim3(nblocks), dim3(192), 0, stream,
                     fcst, obs, accum);
  hipLaunchKernelGGL(fss_final, dim3(1), dim3(64), 0, stream, accum, out);
}

// Round 20
// 227.674 us; speedup vs baseline: 1.0137x; 1.0095x over previous
//
#include <hip/hip_runtime.h>

#define HH 1024
#define WW 1024
#define NB 16
#define NTH 3
#define BAND 128
#define NBAND (HH/BAND)       // 8
#define NSTRIP 11             // strips of 128 cols, 96-col yield
#define ACC_BYTES 4096
#define NEGBIG -1e30f
#define RING 41               // live rows during a group: [g-16, g+24]
#define L10 14.426950408889634f   // 10*log2(e)

typedef unsigned int u32;
typedef _Float16 hv __attribute__((ext_vector_type(2)));

__device__ __forceinline__ hv pkh(float a, float b){
  auto t = __builtin_amdgcn_cvt_pkrtz(a, b);
  hv r; __builtin_memcpy(&r, &t, 4); return r;
}
__device__ __forceinline__ hv bph(int idx4, hv v){
  int s; __builtin_memcpy(&s, &v, 4);
  const int r = __builtin_amdgcn_ds_bpermute(idx4, s);
  hv o; __builtin_memcpy(&o, &r, 4); return o;
}
__device__ __forceinline__ hv swph(hv v){
  u32 u; __builtin_memcpy(&u, &v, 4);
  u = (u >> 16) | (u << 16);
  hv o; __builtin_memcpy(&o, &u, 4); return o;
}
// raw stats: sd += 2*(h.f-h.o)^2 ; sr += h.f^2+h.o^2  (normalized in fss_final)
__device__ __forceinline__ void dstat(hv h, float& sd, float& sr){
  const hv d = h - swph(h);
  sd = __builtin_amdgcn_fdot2(d, d, sd, false);
  sr = __builtin_amdgcn_fdot2(h, h, sr, false);
}

#if __has_builtin(__builtin_amdgcn_rcpf)
#define RCP(x) __builtin_amdgcn_rcpf(x)
#else
#define RCP(x) (1.0f/(x))
#endif
#if __has_builtin(__builtin_amdgcn_exp2f)
#define EXP2(x) __builtin_amdgcn_exp2f(x)
#else
#define EXP2(x) exp2f(x)
#endif

// pack e = 2^(-L10*v) with the 3 obs bits stuffed in mantissa bits [2:0]
__device__ __forceinline__ u32 packeo(float v, float o){
  const float e = EXP2(-L10 * v);           // OOB (v=NEGBIG) -> +inf -> sig 0
  u32 w = __float_as_uint(e) & ~7u;
  w |= (o > 0.0f) ? 1u : 0u;
  w |= (o > 0.5f) ? 2u : 0u;
  w |= (o > 1.0f) ? 4u : 0u;
  return w;
}

__global__ __launch_bounds__(192) void fss_fused(
    const float* __restrict__ F_, const float* __restrict__ O_,
    double* __restrict__ accum)
{
  const int tid = threadIdx.x;
  const int ln  = tid & 63;
  const int t   = tid >> 6;                    // threshold index = wave id
  const int b   = blockIdx.x;
  const int s   = b % NSTRIP;
  const int rem = b / NSTRIP;
  const int band = rem & (NBAND-1);
  const int img  = rem / NBAND;
  const int y0 = band * BAND;
  const int xbase = 96*s - 16;
  const int x0 = xbase + 2*ln;
  const bool colok = ((unsigned)x0 < WW);
  const bool act = (ln >= 8) && (ln < 56) && colok;

  const float K = (t==0) ? 1.0f : ((t==1) ? 148.41315910257660f : 22026.465794806718f);
  const u32 bm = 1u << t;

  const float* F = F_ + (size_t)img*HH*WW;
  const float* O = O_ + (size_t)img*HH*WW;

  __shared__ u32 ring[RING][128];   // e (f32 bits, mantissa[2:0] = obs bits)

  auto slotof = [](int r){ int m = r % RING; return (m < 0) ? m + RING : m; };

  auto stage = [&](int r){
    float2 fv = {NEGBIG, NEGBIG}, ov = {NEGBIG, NEGBIG};
    if ((unsigned)r < HH && colok){
      fv = *(const float2*)&F[(size_t)r*WW + x0];
      ov = *(const float2*)&O[(size_t)r*WW + x0];
    }
    uint2 w; w.x = packeo(fv.x, ov.x); w.y = packeo(fv.y, ov.y);
    *(uint2*)&ring[slotof(r)][2*ln] = w;
  };

  // single-threshold vertical window state + raw stats
  float c9f0=0, c9f1=0, c9o0=0, c9o1=0, c33f0=0, c33f1=0, c33o0=0, c33o1=0;
  float s1d=0, s1r=0, s9d=0, s9r=0, s33d=0, s33r=0;

  const int i_m1=((ln-1)&63)<<2, i_m2=((ln-2)&63)<<2, i_m4=((ln-4)&63)<<2, i_m8=((ln-8)&63)<<2;
  const int i_p1=((ln+1)&63)<<2, i_p2=((ln+2)&63)<<2, i_p7=((ln+7)&63)<<2, i_p8=((ln+8)&63)<<2;

  #define UNP(w, SF, SO) \
    const float SF = RCP(__builtin_fmaf(__uint_as_float((w) & ~7u), K, 1.0f)); \
    const float SO = ((w) & bm) ? 1.f : 0.f;

  // ---- prologue: stage rows y0-16 .. y0+24 (41 rows), split across 3 waves ----
  #pragma unroll 1
  for (int k = t; k < 41; k += 3) stage(y0-16+k);
  __syncthreads();

  // ---- warmup from ring: rows y0-16 .. y0+16 ----
  {
    int sw = slotof(y0-16);
    #pragma unroll 1
    for (int r = y0-16; r <= y0+16; ++r){
      const uint2 w = *(const uint2*)&ring[sw][2*ln];
      sw++; if (sw == RING) sw = 0;
      UNP(w.x, sf0, so0); UNP(w.y, sf1, so1);
      c33f0 += sf0; c33f1 += sf1; c33o0 += so0; c33o1 += so1;
      if (r >= y0-4 && r <= y0+4){ c9f0 += sf0; c9f1 += sf1; c9o0 += so0; c9o1 += so1; }
      if (r >= y0 && r <= y0+4){
        const float d0 = sf0-so0, d1 = sf1-so1;
        s1d += d0*d0 + d1*d1;
        s1r += sf0*sf0 + so0 + sf1*sf1 + so1;    // so^2 == so
      }
    }
  }

  // ---- main loop: {static prefetch, 8 rows, barrier, write, barrier} ----
  int si9 = slotof(y0+5), so9 = slotof(y0-4), si33 = slotof(y0+17), so33 = slotof(y0-16);
  int wrb = slotof(y0+25);

  #pragma unroll 1
  for (int g = y0; g < y0 + BAND; g += 8){
    // wave t stages rows j = 3k + t (k static) -> vf[k]/vo[k] statically indexed
    float2 vf[3], vo[3];
    #pragma unroll
    for (int k = 0; k < 3; ++k){
      vf[k] = make_float2(NEGBIG, NEGBIG);
      vo[k] = make_float2(NEGBIG, NEGBIG);
      const int j = 3*k + t;
      if (j < 8){
        const int r = g + 25 + j;
        if ((unsigned)r < HH && colok){
          vf[k] = *(const float2*)&F[(size_t)r*WW + x0];
          vo[k] = *(const float2*)&O[(size_t)r*WW + x0];
        }
      }
    }

    // 8 compute rows (reads rows [g-16, g+24], all resident)
    #pragma unroll 1
    for (int j = 0; j < 8; ++j){
      const int y = g + j;

      // issue the 4 ring reads FIRST (independent of the bpermute chain)
      const uint2 wi9  = *(const uint2*)&ring[si9 ][2*ln];
      const uint2 wo9  = *(const uint2*)&ring[so9 ][2*ln];
      const uint2 wi33 = *(const uint2*)&ring[si33][2*ln];
      const uint2 wo33 = *(const uint2*)&ring[so33][2*ln];

      // horizontal windows + raw stats for row y
      {
        const hv c0 = pkh(c33f0, c33o0);
        const hv c1 = pkh(c33f1, c33o1);
        hv wv = c0 + c1;                     // pk add replaces pkh(sum,sum)
        wv = wv + bph(i_m1, wv);
        wv = wv + bph(i_m2, wv);
        wv = wv + bph(i_m4, wv);
        wv = wv + bph(i_m8, wv);
        const hv h33_0 = bph(i_p7, wv) + bph(i_p8, c0);
        const hv h33_1 = bph(i_p8, wv) + bph(i_m8, c1);

        const hv q0 = pkh(c9f0, c9o0);
        const hv q1 = pkh(c9f1, c9o1);
        const hv q  = q0 + q1;               // pk add
        const hv mid = q + bph(i_m1, q) + bph(i_p1, q);
        const hv h9_0 = mid + bph(i_m2, q) + bph(i_p2, q0);
        const hv h9_1 = mid + bph(i_p2, q) + bph(i_m2, q1);

        dstat(h9_0,  s9d,  s9r);
        dstat(h9_1,  s9d,  s9r);
        dstat(h33_0, s33d, s33r);
        dstat(h33_1, s33d, s33r);
      }

      // slide vertical windows to center y+1 from the already-read words
      {
        { // entering 9-row (+ k=1 stats)
          UNP(wi9.x, sf0, so0); UNP(wi9.y, sf1, so1);
          c9f0 += sf0; c9f1 += sf1; c9o0 += so0; c9o1 += so1;
          if (y+5 < y0 + BAND){
            const float d0 = sf0-so0, d1 = sf1-so1;
            s1d += d0*d0 + d1*d1;
            s1r += sf0*sf0 + so0 + sf1*sf1 + so1;
          }
        }
        { // leaving 9-row
          UNP(wo9.x, sf0, so0); UNP(wo9.y, sf1, so1);
          c9f0 -= sf0; c9f1 -= sf1; c9o0 -= so0; c9o1 -= so1;
        }
        { // entering 33-row
          UNP(wi33.x, sf0, so0); UNP(wi33.y, sf1, so1);
          c33f0 += sf0; c33f1 += sf1; c33o0 += so0; c33o1 += so1;
        }
        { // leaving 33-row
          UNP(wo33.x, sf0, so0); UNP(wo33.y, sf1, so1);
          c33f0 -= sf0; c33f1 -= sf1; c33o0 -= so0; c33o1 -= so1;
        }
        si9++;  if (si9  == RING) si9  = 0;
        so9++;  if (so9  == RING) so9  = 0;
        si33++; if (si33 == RING) si33 = 0;
        so33++; if (so33 == RING) so33 = 0;
      }
    }

    // slots being written were read (as so33) during THIS group -> barrier,
    // write, barrier (RING=41, R16's best-measured structure)
    __syncthreads();
    #pragma unroll
    for (int k = 0; k < 3; ++k){
      const int j = 3*k + t;
      if (j < 8){
        int wslt = wrb + j; if (wslt >= RING) wslt -= RING;
        uint2 w; w.x = packeo(vf[k].x, vo[k].x); w.y = packeo(vf[k].y, vo[k].y);
        *(uint2*)&ring[wslt][2*ln] = w;
      }
    }
    wrb += 8; if (wrb >= RING) wrb -= RING;
    __syncthreads();
  }

  // ---- mask halo lanes, wave-reduce, per-wave f64 atomics ----
  if (!act){ s1d=0; s1r=0; s9d=0; s9r=0; s33d=0; s33r=0; }
  #define WRED(v) { _Pragma("unroll") \
    for (int d = 32; d; d >>= 1) v += __shfl_down(v, (unsigned)d, 64); }
  WRED(s1d);  WRED(s1r);
  WRED(s9d);  WRED(s9r);
  WRED(s33d); WRED(s33r);
  if (ln == 0){
    double* a = accum + (size_t)(img*NTH + t)*6;
    atomicAdd(&a[0], (double)s1d);
    atomicAdd(&a[1], (double)s1r);
    atomicAdd(&a[2], (double)s9d);
    atomicAdd(&a[3], (double)s9r);
    atomicAdd(&a[4], (double)s33d);
    atomicAdd(&a[5], (double)s33r);
  }
}

__global__ void fss_final(const double* __restrict__ accum, float* __restrict__ out)
{
  if (threadIdx.x == 0 && blockIdx.x == 0){
    const double HW = (double)HH * (double)WW;
    const double msc[3] = {1.0, 2.0*6561.0, 2.0*1185921.0};
    const double rsc[3] = {1.0, 6561.0, 1185921.0};
    double total = 0.0;
    for (int t = 0; t < NTH; ++t){
      for (int k = 0; k < 3; ++k){
        double sum = 0.0;
        for (int img = 0; img < NB; ++img){
          const double* a = accum + (size_t)(img*NTH + t)*6 + (size_t)k*2;
          const double mse  = a[0] / (msc[k]*HW);
          const double mref = a[1] / (rsc[k]*HW);
          sum += 1.0 - mse / (mref + 1e-8);
        }
        total += sum / (double)NB;
      }
    }
    out[0] = (float)(1.0 - total/9.0);
  }
}

extern "C" void kernel_launch(void* const* d_in, const int* in_sizes, int n_in,
                              void* d_out, int out_size, void* d_ws, size_t ws_size,
                              hipStream_t stream)
{
  const float* fcst = (const float*)d_in[0];
  const float* obs  = (const float*)d_in[1];
  float* out = (float*)d_out;
  double* accum = (double*)d_ws;

  const int nblocks = NSTRIP * NBAND * NB;   // 1408 blocks x 3 waves

  hipMemsetAsync(d_ws, 0, ACC_BYTES, stream);
  hipLaunchKernelGGL(fss_fused, dim3(nblocks), dim3(192), 0, stream,
                     fcst, obs, accum);
  hipLaunchKernelGGL(fss_final, dim3(1), dim3(64), 0, stream, accum, out);
}